// Round 4
// baseline (290.229 us; speedup 1.0000x reference)
//
#include <hip/hip_runtime.h>
#include <stdint.h>

// True vector type so __builtin_nontemporal_{load,store} accepts it.
typedef uint32_t u32x4 __attribute__((ext_vector_type(4)));

// ---------- exact numpy-compatible fp16 add on raw bit patterns ----------

// fp16 bits -> f32 (exact, matches npy_halfbits_to_floatbits).
__device__ __forceinline__ float h2f(uint32_t h) {
    uint32_t s = (h & 0x8000u) << 16;
    uint32_t e = (h >> 10) & 0x1fu;
    uint32_t m = h & 0x3ffu;
    if (e == 0) {
        float v = (float)m * 5.9604644775390625e-08f;  // m * 2^-24, exact
        return __uint_as_float(s | __float_as_uint(v));
    }
    uint32_t fb;
    if (e == 31) fb = s | 0x7f800000u | (m << 13);
    else         fb = s | ((e + 112u) << 23) | (m << 13);
    return __uint_as_float(fb);
}

// f32 bits -> fp16 bits, RNE: port of numpy npy_floatbits_to_halfbits.
__device__ __forceinline__ uint32_t f2h(uint32_t f) {
    uint32_t h_sgn = (f & 0x80000000u) >> 16;
    uint32_t f_exp = f & 0x7f800000u;
    uint32_t f_sig;

    if (f_exp >= 0x47800000u) {
        if (f_exp == 0x7f800000u) {
            f_sig = f & 0x007fffffu;
            if (f_sig != 0u) {
                uint32_t ret = 0x7c00u + (f_sig >> 13);
                if (ret == 0x7c00u) ret++;
                return h_sgn + ret;
            }
            return h_sgn + 0x7c00u;
        }
        return h_sgn + 0x7c00u;                // overflow -> signed inf
    }

    if (f_exp <= 0x38000000u) {                // subnormal half or zero
        if (f_exp < 0x33000000u) return h_sgn; // underflow -> signed zero
        uint32_t fe = f_exp >> 23;
        f_sig = 0x00800000u + (f & 0x007fffffu);
        f_sig >>= (113u - fe);
        if (((f_sig & 0x00003fffu) != 0x00001000u) || (f & 0x000007ffu)) {
            f_sig += 0x00001000u;              // RNE
        }
        return h_sgn + (f_sig >> 13);
    }

    uint32_t h_exp = (f_exp - 0x38000000u) >> 13;
    f_sig = f & 0x007fffffu;
    if ((f_sig & 0x00003fffu) != 0x00001000u) {
        f_sig += 0x00001000u;                  // RNE
    }
    uint32_t h_sig = f_sig >> 13;
    return h_sgn + h_exp + h_sig;              // rounding spill is correct via add
}

// Full fp16 add with x86-addss / numpy special-case semantics.
__device__ __forceinline__ uint32_t fp16_add(uint32_t ua, uint32_t ub) {
    uint32_t ea = ua & 0x7fffu;
    uint32_t eb = ub & 0x7fffu;
    uint32_t r = f2h(__float_as_uint(h2f(ua) + h2f(ub)));
    if (ea == 0x7c00u && (ua ^ ub) == 0x8000u) r = 0xfe00u;  // inf + (-inf)
    if (eb > 0x7c00u) r = ub | 0x0200u;                      // NaN quieting,
    if (ea > 0x7c00u) r = ua | 0x0200u;                      // src1 (A) wins
    return r;
}

// ---------- spike <-> nibble helpers ----------

__device__ __forceinline__ uint32_t pack4(u32x4 c, int top) {
    uint32_t u = 0;
    u |= ((c.x >> 23) & 1u) << top;
    u |= ((c.y >> 23) & 1u) << (top - 1);
    u |= ((c.z >> 23) & 1u) << (top - 2);
    u |= ((c.w >> 23) & 1u) << (top - 3);
    return u;
}

__device__ __forceinline__ u32x4 unpack4(uint32_t r, int top) {
    u32x4 o;
    o.x = ((r >> top)       & 1u) * 0x3f800000u;
    o.y = ((r >> (top - 1)) & 1u) * 0x3f800000u;
    o.z = ((r >> (top - 2)) & 1u) * 0x3f800000u;
    o.w = ((r >> (top - 3)) & 1u) * 0x3f800000u;
    return o;
}

// OR-reduce across aligned groups of 4 lanes (xor 1/2 lower to DPP quad_perm:
// pure VALU, no LDS/lgkmcnt on the critical path).
__device__ __forceinline__ uint32_t orreduce4(uint32_t v) {
    v |= __shfl_xor(v, 1, 64);
    v |= __shfl_xor(v, 2, 64);
    return v;
}

// ---------- kernel ----------
// Block = 256 threads covers 512 rows (= 2048 uint4 per array). All 16 nt
// loads (256 B/thread in flight) issue before any compute to maximize MLP;
// then 8 word-assemblies (4-lane DPP OR), 8 adds, 8 nt stores. Fully
// coalesced; non-temporal everywhere (A/B read-once, O write-once) so our
// streams don't displace L3-resident input lines.
__global__ __launch_bounds__(256) void spike_fp16_add_kernel(
    const u32x4* __restrict__ A, const u32x4* __restrict__ B,
    u32x4* __restrict__ O)
{
    const int t = threadIdx.x;
    const int c = t & 3;
    const int top = 15 - 4 * c;                 // nibble position for chunk c
    const size_t base = (size_t)blockIdx.x * 2048;

    u32x4 a[8], b[8];
#pragma unroll
    for (int k = 0; k < 8; ++k) a[k] = __builtin_nontemporal_load(&A[base + t + 256 * k]);
#pragma unroll
    for (int k = 0; k < 8; ++k) b[k] = __builtin_nontemporal_load(&B[base + t + 256 * k]);

    uint32_t r[8];
#pragma unroll
    for (int k = 0; k < 8; ++k) {
        uint32_t ua = orreduce4(pack4(a[k], top));
        uint32_t ub = orreduce4(pack4(b[k], top));
        r[k] = fp16_add(ua, ub);
    }

#pragma unroll
    for (int k = 0; k < 8; ++k)
        __builtin_nontemporal_store(unpack4(r[k], top), &O[base + t + 256 * k]);
}

extern "C" void kernel_launch(void* const* d_in, const int* in_sizes, int n_in,
                              void* d_out, int out_size, void* d_ws, size_t ws_size,
                              hipStream_t stream) {
    const u32x4* A = (const u32x4*)d_in[0];
    const u32x4* B = (const u32x4*)d_in[1];
    u32x4* O = (u32x4*)d_out;
    int rows = in_sizes[0] / 16;               // 2,097,152 (multiple of 512)
    int blocks = rows / 512;                   // 4096
    spike_fp16_add_kernel<<<blocks, 256, 0, stream>>>(A, B, O);
}